// Round 19
// baseline (44.947 us; speedup 1.0000x reference)
//
#include <hip/hip_runtime.h>
#include <hip/hip_bf16.h>
#include <cmath>

#define BATCH 8
#define ZDIM 512
#define SDIM 256
#define LVL 16
#define TSZ 16384
#define NPIX 65536   // 256*256
#define P2H 2654435761u

typedef __attribute__((ext_vector_type(8))) short bf16x8;
typedef __attribute__((ext_vector_type(4))) float floatx4;
typedef __attribute__((ext_vector_type(4))) unsigned uintx4;
typedef unsigned short ushort_t;

// ws layout per batch (ushort units): 14 A-frags (weightsᵀ), hi at f*1024+lane*8,
// lo at +512.  f=0..3: W0ᵀ m-blocks.  f=4+2m'+kf: W1ᵀ.  f=12+kf: W2ᵀ.
// ch(m,r) = 8*(r>>2)+(r&3)+4*(m&1)+32*(m>>1) baked in (R12-verified).
#define BSTRIDE 14336
// total ws use: 8*14336*2 = 229376 B (proven bound, R5)

__device__ __forceinline__ float lrelu(float x) {
    return (x >= 0.0f ? x : 0.2f * x) * 1.41421356237309515f;
}
__device__ __forceinline__ ushort_t f2bf(float x) {   // RNE f32->bf16
    unsigned u = __builtin_bit_cast(unsigned, x);
    u += 0x7fffu + ((u >> 16) & 1u);
    return (ushort_t)(u >> 16);
}
__device__ __forceinline__ float bf2f(ushort_t h) {
    unsigned u = ((unsigned)h) << 16;
    return __builtin_bit_cast(float, u);
}
// HW packed f32->bf16 (RNE, identical rounding to f2bf); low16 = a, high16 = b.
__device__ __forceinline__ unsigned cvt_pk_bf16(float a, float b) {
    unsigned r;
    asm("v_cvt_pk_bf16_f32 %0, %1, %2" : "=v"(r) : "v"(a), "v"(b));
    return r;
}

struct ResPack { float rm1[LVL]; };

// 1024-thread k_setup (R16: passing, byte-identical).
__global__ __launch_bounds__(1024) void k_setup(
    const float* __restrict__ z,
    const float* __restrict__ w1, const float* __restrict__ b1,
    const float* __restrict__ w2, const float* __restrict__ b2,
    const float* __restrict__ w3, const float* __restrict__ b3,
    const float* __restrict__ gen_w,
    const float* __restrict__ a0w, const float* __restrict__ a0b,
    const float* __restrict__ m0w,
    const float* __restrict__ a1w, const float* __restrict__ a1b,
    const float* __restrict__ m1w,
    const float* __restrict__ a2w, const float* __restrict__ a2b,
    const float* __restrict__ m2w,
    ushort_t* __restrict__ wsf)
{
    const int b = blockIdx.x;
    const int t = threadIdx.x;
    __shared__ float red[1024];
    __shared__ float sA[SDIM];
    __shared__ float sB[SDIM];
    __shared__ float zb[ZDIM];
    __shared__ float sc0[32], sc1[64], sc2[64], modv[32];
    __shared__ float d0[64], d1[64], d2[4];
    __shared__ float wl0[32 * 64];
    __shared__ float wl1[64 * 64];
    __shared__ float wl2[64 * 16];

    if (t < ZDIM) zb[t] = z[b * ZDIM + t];
    __syncthreads();

    const int col = t & 255, ks = t >> 8;

    // ---- FC1: [512]->[256], 4-way K-split (chunk 128)
    {
        const float* xb = zb + ks * 128;
        const float* wp = w1 + (ks * 128) * SDIM + col;
        float a0 = 0.f, a1 = 0.f, a2 = 0.f, a3 = 0.f;
#pragma unroll 8
        for (int k = 0; k < 128; k += 4) {
            a0 = fmaf(xb[k + 0], wp[(k + 0) * SDIM], a0);
            a1 = fmaf(xb[k + 1], wp[(k + 1) * SDIM], a1);
            a2 = fmaf(xb[k + 2], wp[(k + 2) * SDIM], a2);
            a3 = fmaf(xb[k + 3], wp[(k + 3) * SDIM], a3);
        }
        red[t] = (a0 + a1) + (a2 + a3);
    }
    __syncthreads();
    if (t < 256)
        sA[t] = lrelu(b1[t] + ((red[t] + red[t + 256]) + (red[t + 512] + red[t + 768])));
    __syncthreads();

    // ---- FC2: [256]->[256], chunk 64
    {
        const float* xb = sA + ks * 64;
        const float* wp = w2 + (ks * 64) * SDIM + col;
        float a0 = 0.f, a1 = 0.f, a2 = 0.f, a3 = 0.f;
#pragma unroll 8
        for (int k = 0; k < 64; k += 4) {
            a0 = fmaf(xb[k + 0], wp[(k + 0) * SDIM], a0);
            a1 = fmaf(xb[k + 1], wp[(k + 1) * SDIM], a1);
            a2 = fmaf(xb[k + 2], wp[(k + 2) * SDIM], a2);
            a3 = fmaf(xb[k + 3], wp[(k + 3) * SDIM], a3);
        }
        red[t] = (a0 + a1) + (a2 + a3);
    }
    __syncthreads();
    if (t < 256)
        sB[t] = lrelu(b2[t] + ((red[t] + red[t + 256]) + (red[t + 512] + red[t + 768])));
    __syncthreads();

    // ---- FC3: [256]->[256], chunk 64 -> final style in sA
    {
        const float* xb = sB + ks * 64;
        const float* wp = w3 + (ks * 64) * SDIM + col;
        float a0 = 0.f, a1 = 0.f, a2 = 0.f, a3 = 0.f;
#pragma unroll 8
        for (int k = 0; k < 64; k += 4) {
            a0 = fmaf(xb[k + 0], wp[(k + 0) * SDIM], a0);
            a1 = fmaf(xb[k + 1], wp[(k + 1) * SDIM], a1);
            a2 = fmaf(xb[k + 2], wp[(k + 2) * SDIM], a2);
            a3 = fmaf(xb[k + 3], wp[(k + 3) * SDIM], a3);
        }
        red[t] = (a0 + a1) + (a2 + a3);
    }
    __syncthreads();
    if (t < 256)
        sA[t] = lrelu(b3[t] + ((red[t] + red[t + 256]) + (red[t + 512] + red[t + 768])));
    __syncthreads();

    // ---- scales (modv/sc0/sc1/sc2): 192 outputs x 4 K-split (chunk 64)
    {
        float r = 0.0f;
        if (col < 192) {
            const float* s = sA + ks * 64;
            const float* wp;
            int stride;
            if (col < 32)       { const int lv = col >> 1, f = col & 1; wp = gen_w + lv * 512 + f + (ks * 64) * 2; stride = 2; }
            else if (col < 64)  { wp = a0w + (col - 32) + (ks * 64) * 32; stride = 32; }
            else if (col < 128) { wp = a1w + (col - 64) + (ks * 64) * 64; stride = 64; }
            else                { wp = a2w + (col - 128) + (ks * 64) * 64; stride = 64; }
            float a0 = 0.f, a1 = 0.f, a2 = 0.f, a3 = 0.f;
#pragma unroll 8
            for (int k = 0; k < 64; k += 4) {
                a0 = fmaf(s[k + 0], wp[(k + 0) * stride], a0);
                a1 = fmaf(s[k + 1], wp[(k + 1) * stride], a1);
                a2 = fmaf(s[k + 2], wp[(k + 2) * stride], a2);
                a3 = fmaf(s[k + 3], wp[(k + 3) * stride], a3);
            }
            r = (a0 + a1) + (a2 + a3);
        }
        red[t] = r;
    }
    __syncthreads();
    if (t < 192) {
        const float v = (red[t] + red[t + 256]) + (red[t + 512] + red[t + 768]);
        if (t < 32)       modv[t] = 1.0f + v;
        else if (t < 64)  sc0[t - 32] = a0b[t - 32] + v;
        else if (t < 128) sc1[t - 64] = a1b[t - 64] + v;
        else              sc2[t - 128] = a2b[t - 128] + v;
    }
    __syncthreads();

    // ---- demod sums: d0 (K=32, chunk 8), d1/d2 (K=64, chunk 16), 4-way split
    {
        float r = 0.0f;
        if (col < 64) {
            float acc = 0.f;
#pragma unroll
            for (int i = ks * 8; i < ks * 8 + 8; ++i) {
                const float v = m0w[i * 64 + col] * sc0[i];
                acc = fmaf(v, v, acc);
            }
            r = acc;
        } else if (col < 128) {
            const int j = col - 64;
            float acc = 0.f;
#pragma unroll
            for (int i = ks * 16; i < ks * 16 + 16; ++i) {
                const float v = m1w[i * 64 + j] * sc1[i];
                acc = fmaf(v, v, acc);
            }
            r = acc;
        } else if (col < 131) {
            const int j = col - 128;
            float acc = 0.f;
#pragma unroll
            for (int i = ks * 16; i < ks * 16 + 16; ++i) {
                const float v = m2w[i * 3 + j] * sc2[i];
                acc = fmaf(v, v, acc);
            }
            r = acc;
        }
        red[t] = r;
    }
    __syncthreads();
    if (t < 131) {
        const float s2 = (red[t] + red[t + 256]) + (red[t + 512] + red[t + 768]);
        if (t < 64)       d0[t] = rsqrtf(s2 + 1e-8f);
        else if (t < 128) d1[t - 64] = rsqrtf(s2 + 1e-8f);
        else              d2[t - 128] = rsqrtf(s2 + 1e-8f);
    }
    __syncthreads();

    // ---- effective weights
    for (int e = t; e < 2048; e += 1024) {
        const int i = e >> 6, j = e & 63;
        wl0[e] = m0w[e] * sc0[i] * d0[j] * modv[i];
    }
    for (int e = t; e < 4096; e += 1024) {
        const int i = e >> 6, j = e & 63;
        wl1[e] = m1w[e] * sc1[i] * d1[j];
    }
    {
        const int i = t >> 4, j = t & 15;
        wl2[t] = (j < 3) ? m2w[i * 3 + j] * sc2[i] * d2[j] : 0.0f;
    }
    __syncthreads();

    // ---- Pack Wᵀ A-fragments (R12/R13-verified layout, byte-identical)
    ushort_t* outb = wsf + b * BSTRIDE;
    if (t < 896) {
        const int f = t >> 6, lane = t & 63;
        const int gg = lane >> 4, cc = lane & 15;   // cc = A row, k = 8*gg+e
        bf16x8 hv, lv;
#pragma unroll
        for (int e = 0; e < 8; ++e) {
            float wv;
            if (f < 4) {
                const int m = f;
                const int ch = 8 * (cc >> 2) + (cc & 3) + 4 * (m & 1) + 32 * (m >> 1);
                wv = wl0[(8 * gg + e) * 64 + ch];
            } else if (f < 12) {
                const int m = (f - 4) >> 1, kf = (f - 4) & 1;
                const int ch = 8 * (cc >> 2) + (cc & 3) + 4 * (m & 1) + 32 * (m >> 1);
                wv = wl1[(32 * kf + 8 * gg + e) * 64 + ch];
            } else {
                const int kf = f - 12;
                wv = wl2[(32 * kf + 8 * gg + e) * 16 + cc];
            }
            const ushort_t hh = f2bf(wv);
            hv[e] = (short)hh;
            lv[e] = (short)f2bf(wv - bf2f(hh));
        }
        *(bf16x8*)(outb + f * 1024 + lane * 8) = hv;
        *(bf16x8*)(outb + f * 1024 + 512 + lane * 8) = lv;
    }
}

// Swapped-operand MFMA chain (R17 structure, passing). R19: batch loop split
// across grid.y (2 halves of 4 batches) -> 2x resident waves for latency hiding.
__global__ __launch_bounds__(256) void k_main(
    const float* __restrict__ base_tables,
    const ushort_t* __restrict__ wsf,
    const float* __restrict__ m0b,
    const float* __restrict__ m1b,
    const float* __restrict__ m2b,
    float* __restrict__ out,
    ResPack rp)
{
    const int t = threadIdx.x;
    const int w = t >> 6;
    const int l = t & 63;
    const int g = l >> 4;
    const int c = l & 15;
    const int tile_base = blockIdx.x * 64 + w * 16;
    const int b0 = blockIdx.y * 4;   // this block's 4 batches

    const int apx = tile_base + c;
    const float cx = ((float)(apx & 255) + 0.5f) * (1.0f / 256.0f);
    const float cy = ((float)(apx >> 8) + 0.5f) * (1.0f / 256.0f);
    bf16x8 rf_hi;
#pragma unroll
    for (int d = 0; d < 4; ++d) {
        float r1 = rp.rm1[d];
        r1 = (g == 1) ? rp.rm1[4 + d] : r1;
        r1 = (g == 2) ? rp.rm1[8 + d] : r1;
        r1 = (g == 3) ? rp.rm1[12 + d] : r1;
        const float sx = cx * r1, sy = cy * r1;
        const float pxf = floorf(sx), pyf = floorf(sy);
        const float fx = sx - pxf, fy = sy - pyf;
        const unsigned x0 = (unsigned)pxf, y0 = (unsigned)pyf;
        const unsigned x1 = x0 + 1u, y1 = y0 + 1u;
        const unsigned hy0 = y0 * P2H, hy1 = y1 * P2H;
        const float2* tab = reinterpret_cast<const float2*>(base_tables) + ((4 * g + d) << 14);
        const float2 f00 = tab[(x0 ^ hy0) & (TSZ - 1)];
        const float2 f01 = tab[(x0 ^ hy1) & (TSZ - 1)];
        const float2 f10 = tab[(x1 ^ hy0) & (TSZ - 1)];
        const float2 f11 = tab[(x1 ^ hy1) & (TSZ - 1)];
        const float w00 = (1.0f - fx) * (1.0f - fy);
        const float w01 = (1.0f - fx) * fy;
        const float w10 = fx * (1.0f - fy);
        const float w11 = fx * fy;
        const float v0 = w00 * f00.x + w01 * f01.x + w10 * f10.x + w11 * f11.x;
        const float v1 = w00 * f00.y + w01 * f01.y + w10 * f10.y + w11 * f11.y;
        rf_hi[2 * d]     = (short)f2bf(v0);
        rf_hi[2 * d + 1] = (short)f2bf(v1);
    }

    float b0v[4][4], b1v[4][4];
#pragma unroll
    for (int m = 0; m < 4; ++m)
#pragma unroll
        for (int q = 0; q < 4; ++q) {
            const int ch = 8 * g + q + 4 * (m & 1) + 32 * (m >> 1);
            b0v[m][q] = m0b[ch];
            b1v[m][q] = m1b[ch];
        }
    const floatx4 acc2init = (g == 0)
        ? (floatx4){ m2b[0], m2b[1], m2b[2], 0.0f }
        : (floatx4){ 0.0f, 0.0f, 0.0f, 0.0f };

#pragma unroll 2
    for (int bi = 0; bi < 4; ++bi) {
        const int b = b0 + bi;
        const ushort_t* F = wsf + b * BSTRIDE + l * 8;
#define LDF(fi, which) (*(const bf16x8*)(F + (fi) * 1024 + (which) * 512))

        // ---- layer 0: W hi only
        floatx4 acc0[4];
#pragma unroll
        for (int m = 0; m < 4; ++m) {
            acc0[m] = (floatx4){ b0v[m][0], b0v[m][1], b0v[m][2], b0v[m][3] };
            acc0[m] = __builtin_amdgcn_mfma_f32_16x16x32_bf16(LDF(m, 0), rf_hi, acc0[m], 0, 0, 0);
        }
        uintx4 u0, u1;
#pragma unroll
        for (int j = 0; j < 4; ++j) {
            u0[j] = cvt_pk_bf16(lrelu(acc0[j >> 1][(j & 1) * 2 + 0]),
                                lrelu(acc0[j >> 1][(j & 1) * 2 + 1]));
            u1[j] = cvt_pk_bf16(lrelu(acc0[2 + (j >> 1)][(j & 1) * 2 + 0]),
                                lrelu(acc0[2 + (j >> 1)][(j & 1) * 2 + 1]));
        }
        const bf16x8 h1f0 = __builtin_bit_cast(bf16x8, u0);
        const bf16x8 h1f1 = __builtin_bit_cast(bf16x8, u1);

        // ---- layer 1: W hi only
        floatx4 acc1[4];
#pragma unroll
        for (int m = 0; m < 4; ++m) {
            acc1[m] = (floatx4){ b1v[m][0], b1v[m][1], b1v[m][2], b1v[m][3] };
            acc1[m] = __builtin_amdgcn_mfma_f32_16x16x32_bf16(LDF(4 + 2 * m, 0), h1f0, acc1[m], 0, 0, 0);
            acc1[m] = __builtin_amdgcn_mfma_f32_16x16x32_bf16(LDF(5 + 2 * m, 0), h1f1, acc1[m], 0, 0, 0);
        }
        uintx4 v0, v1;
#pragma unroll
        for (int j = 0; j < 4; ++j) {
            v0[j] = cvt_pk_bf16(lrelu(acc1[j >> 1][(j & 1) * 2 + 0]),
                                lrelu(acc1[j >> 1][(j & 1) * 2 + 1]));
            v1[j] = cvt_pk_bf16(lrelu(acc1[2 + (j >> 1)][(j & 1) * 2 + 0]),
                                lrelu(acc1[2 + (j >> 1)][(j & 1) * 2 + 1]));
        }
        const bf16x8 h2f0 = __builtin_bit_cast(bf16x8, v0);
        const bf16x8 h2f1 = __builtin_bit_cast(bf16x8, v1);

        // ---- layer 2: W hi only
        floatx4 acc2 = acc2init;
        acc2 = __builtin_amdgcn_mfma_f32_16x16x32_bf16(LDF(12, 0), h2f0, acc2, 0, 0, 0);
        acc2 = __builtin_amdgcn_mfma_f32_16x16x32_bf16(LDF(13, 0), h2f1, acc2, 0, 0, 0);

        if (g == 0) {
            out[(b * 3 + 0) * NPIX + tile_base + c] = acc2[0];
            out[(b * 3 + 1) * NPIX + tile_base + c] = acc2[1];
            out[(b * 3 + 2) * NPIX + tile_base + c] = acc2[2];
        }
#undef LDF
    }
}

extern "C" void kernel_launch(void* const* d_in, const int* in_sizes, int n_in,
                              void* d_out, int out_size, void* d_ws, size_t ws_size,
                              hipStream_t stream) {
    const float* z    = (const float*)d_in[0];
    const float* w1   = (const float*)d_in[1];
    const float* b1   = (const float*)d_in[2];
    const float* w2   = (const float*)d_in[3];
    const float* b2   = (const float*)d_in[4];
    const float* w3   = (const float*)d_in[5];
    const float* b3   = (const float*)d_in[6];
    const float* bt   = (const float*)d_in[7];
    const float* genw = (const float*)d_in[8];
    const float* a0w  = (const float*)d_in[9];
    const float* a0b  = (const float*)d_in[10];
    const float* m0w  = (const float*)d_in[11];
    const float* m0b  = (const float*)d_in[12];
    const float* a1w  = (const float*)d_in[13];
    const float* a1b  = (const float*)d_in[14];
    const float* m1w  = (const float*)d_in[15];
    const float* m1b  = (const float*)d_in[16];
    const float* a2w  = (const float*)d_in[17];
    const float* a2b  = (const float*)d_in[18];
    const float* m2w  = (const float*)d_in[19];
    const float* m2b  = (const float*)d_in[20];
    ushort_t* wsf = (ushort_t*)d_ws;
    float* out = (float*)d_out;

    ResPack rp;
    const double bfac = exp((log(256.0) - log(16.0)) / 15.0);
    for (int lv = 0; lv < LVL; ++lv) {
        const double v = floor(16.0 * pow(bfac, (double)lv));
        rp.rm1[lv] = (float)v - 1.0f;
    }

    hipLaunchKernelGGL(k_setup, dim3(BATCH), dim3(1024), 0, stream,
                       z, w1, b1, w2, b2, w3, b3, genw,
                       a0w, a0b, m0w, a1w, a1b, m1w, a2w, a2b, m2w, wsf);

    hipLaunchKernelGGL(k_main, dim3(NPIX / 64, 2), dim3(256), 0, stream,
                       bt, wsf, m0b, m1b, m2b, out, rp);
}

// Round 21
// 42.322 us; speedup vs baseline: 1.0620x; 1.0620x over previous
//
#include <hip/hip_runtime.h>
#include <hip/hip_bf16.h>
#include <cmath>

#define BATCH 8
#define ZDIM 512
#define SDIM 256
#define LVL 16
#define TSZ 16384
#define NPIX 65536   // 256*256
#define P2H 2654435761u

typedef __attribute__((ext_vector_type(8))) short bf16x8;
typedef __attribute__((ext_vector_type(4))) float floatx4;
typedef __attribute__((ext_vector_type(4))) unsigned uintx4;
typedef unsigned short ushort_t;

// ws layout per batch (ushort units): 14 A-frags (weightsᵀ), hi at f*1024+lane*8,
// lo at +512.  f=0..3: W0ᵀ m-blocks.  f=4+2m'+kf: W1ᵀ.  f=12+kf: W2ᵀ.
// ch(m,r) = 8*(r>>2)+(r&3)+4*(m&1)+32*(m>>1) baked in (R12-verified).
#define BSTRIDE 14336
// total ws use: 8*14336*2 = 229376 B (proven bound, R5)

__device__ __forceinline__ float lrelu(float x) {
    return (x >= 0.0f ? x : 0.2f * x) * 1.41421356237309515f;
}
__device__ __forceinline__ ushort_t f2bf(float x) {   // RNE f32->bf16
    unsigned u = __builtin_bit_cast(unsigned, x);
    u += 0x7fffu + ((u >> 16) & 1u);
    return (ushort_t)(u >> 16);
}
__device__ __forceinline__ float bf2f(ushort_t h) {
    unsigned u = ((unsigned)h) << 16;
    return __builtin_bit_cast(float, u);
}
// HW packed f32->bf16 (RNE, identical rounding to f2bf); low16 = a, high16 = b.
__device__ __forceinline__ unsigned cvt_pk_bf16(float a, float b) {
    unsigned r;
    asm("v_cvt_pk_bf16_f32 %0, %1, %2" : "=v"(r) : "v"(a), "v"(b));
    return r;
}

struct ResPack { float rm1[LVL]; };

// 1024-thread k_setup (R16: passing, byte-identical).
__global__ __launch_bounds__(1024) void k_setup(
    const float* __restrict__ z,
    const float* __restrict__ w1, const float* __restrict__ b1,
    const float* __restrict__ w2, const float* __restrict__ b2,
    const float* __restrict__ w3, const float* __restrict__ b3,
    const float* __restrict__ gen_w,
    const float* __restrict__ a0w, const float* __restrict__ a0b,
    const float* __restrict__ m0w,
    const float* __restrict__ a1w, const float* __restrict__ a1b,
    const float* __restrict__ m1w,
    const float* __restrict__ a2w, const float* __restrict__ a2b,
    const float* __restrict__ m2w,
    ushort_t* __restrict__ wsf)
{
    const int b = blockIdx.x;
    const int t = threadIdx.x;
    __shared__ float red[1024];
    __shared__ float sA[SDIM];
    __shared__ float sB[SDIM];
    __shared__ float zb[ZDIM];
    __shared__ float sc0[32], sc1[64], sc2[64], modv[32];
    __shared__ float d0[64], d1[64], d2[4];
    __shared__ float wl0[32 * 64];
    __shared__ float wl1[64 * 64];
    __shared__ float wl2[64 * 16];

    if (t < ZDIM) zb[t] = z[b * ZDIM + t];
    __syncthreads();

    const int col = t & 255, ks = t >> 8;

    // ---- FC1: [512]->[256], 4-way K-split (chunk 128)
    {
        const float* xb = zb + ks * 128;
        const float* wp = w1 + (ks * 128) * SDIM + col;
        float a0 = 0.f, a1 = 0.f, a2 = 0.f, a3 = 0.f;
#pragma unroll 8
        for (int k = 0; k < 128; k += 4) {
            a0 = fmaf(xb[k + 0], wp[(k + 0) * SDIM], a0);
            a1 = fmaf(xb[k + 1], wp[(k + 1) * SDIM], a1);
            a2 = fmaf(xb[k + 2], wp[(k + 2) * SDIM], a2);
            a3 = fmaf(xb[k + 3], wp[(k + 3) * SDIM], a3);
        }
        red[t] = (a0 + a1) + (a2 + a3);
    }
    __syncthreads();
    if (t < 256)
        sA[t] = lrelu(b1[t] + ((red[t] + red[t + 256]) + (red[t + 512] + red[t + 768])));
    __syncthreads();

    // ---- FC2: [256]->[256], chunk 64
    {
        const float* xb = sA + ks * 64;
        const float* wp = w2 + (ks * 64) * SDIM + col;
        float a0 = 0.f, a1 = 0.f, a2 = 0.f, a3 = 0.f;
#pragma unroll 8
        for (int k = 0; k < 64; k += 4) {
            a0 = fmaf(xb[k + 0], wp[(k + 0) * SDIM], a0);
            a1 = fmaf(xb[k + 1], wp[(k + 1) * SDIM], a1);
            a2 = fmaf(xb[k + 2], wp[(k + 2) * SDIM], a2);
            a3 = fmaf(xb[k + 3], wp[(k + 3) * SDIM], a3);
        }
        red[t] = (a0 + a1) + (a2 + a3);
    }
    __syncthreads();
    if (t < 256)
        sB[t] = lrelu(b2[t] + ((red[t] + red[t + 256]) + (red[t + 512] + red[t + 768])));
    __syncthreads();

    // ---- FC3: [256]->[256], chunk 64 -> final style in sA
    {
        const float* xb = sB + ks * 64;
        const float* wp = w3 + (ks * 64) * SDIM + col;
        float a0 = 0.f, a1 = 0.f, a2 = 0.f, a3 = 0.f;
#pragma unroll 8
        for (int k = 0; k < 64; k += 4) {
            a0 = fmaf(xb[k + 0], wp[(k + 0) * SDIM], a0);
            a1 = fmaf(xb[k + 1], wp[(k + 1) * SDIM], a1);
            a2 = fmaf(xb[k + 2], wp[(k + 2) * SDIM], a2);
            a3 = fmaf(xb[k + 3], wp[(k + 3) * SDIM], a3);
        }
        red[t] = (a0 + a1) + (a2 + a3);
    }
    __syncthreads();
    if (t < 256)
        sA[t] = lrelu(b3[t] + ((red[t] + red[t + 256]) + (red[t + 512] + red[t + 768])));
    __syncthreads();

    // ---- scales (modv/sc0/sc1/sc2): 192 outputs x 4 K-split (chunk 64)
    {
        float r = 0.0f;
        if (col < 192) {
            const float* s = sA + ks * 64;
            const float* wp;
            int stride;
            if (col < 32)       { const int lv = col >> 1, f = col & 1; wp = gen_w + lv * 512 + f + (ks * 64) * 2; stride = 2; }
            else if (col < 64)  { wp = a0w + (col - 32) + (ks * 64) * 32; stride = 32; }
            else if (col < 128) { wp = a1w + (col - 64) + (ks * 64) * 64; stride = 64; }
            else                { wp = a2w + (col - 128) + (ks * 64) * 64; stride = 64; }
            float a0 = 0.f, a1 = 0.f, a2 = 0.f, a3 = 0.f;
#pragma unroll 8
            for (int k = 0; k < 64; k += 4) {
                a0 = fmaf(s[k + 0], wp[(k + 0) * stride], a0);
                a1 = fmaf(s[k + 1], wp[(k + 1) * stride], a1);
                a2 = fmaf(s[k + 2], wp[(k + 2) * stride], a2);
                a3 = fmaf(s[k + 3], wp[(k + 3) * stride], a3);
            }
            r = (a0 + a1) + (a2 + a3);
        }
        red[t] = r;
    }
    __syncthreads();
    if (t < 192) {
        const float v = (red[t] + red[t + 256]) + (red[t + 512] + red[t + 768]);
        if (t < 32)       modv[t] = 1.0f + v;
        else if (t < 64)  sc0[t - 32] = a0b[t - 32] + v;
        else if (t < 128) sc1[t - 64] = a1b[t - 64] + v;
        else              sc2[t - 128] = a2b[t - 128] + v;
    }
    __syncthreads();

    // ---- demod sums: d0 (K=32, chunk 8), d1/d2 (K=64, chunk 16), 4-way split
    {
        float r = 0.0f;
        if (col < 64) {
            float acc = 0.f;
#pragma unroll
            for (int i = ks * 8; i < ks * 8 + 8; ++i) {
                const float v = m0w[i * 64 + col] * sc0[i];
                acc = fmaf(v, v, acc);
            }
            r = acc;
        } else if (col < 128) {
            const int j = col - 64;
            float acc = 0.f;
#pragma unroll
            for (int i = ks * 16; i < ks * 16 + 16; ++i) {
                const float v = m1w[i * 64 + j] * sc1[i];
                acc = fmaf(v, v, acc);
            }
            r = acc;
        } else if (col < 131) {
            const int j = col - 128;
            float acc = 0.f;
#pragma unroll
            for (int i = ks * 16; i < ks * 16 + 16; ++i) {
                const float v = m2w[i * 3 + j] * sc2[i];
                acc = fmaf(v, v, acc);
            }
            r = acc;
        }
        red[t] = r;
    }
    __syncthreads();
    if (t < 131) {
        const float s2 = (red[t] + red[t + 256]) + (red[t + 512] + red[t + 768]);
        if (t < 64)       d0[t] = rsqrtf(s2 + 1e-8f);
        else if (t < 128) d1[t - 64] = rsqrtf(s2 + 1e-8f);
        else              d2[t - 128] = rsqrtf(s2 + 1e-8f);
    }
    __syncthreads();

    // ---- effective weights
    for (int e = t; e < 2048; e += 1024) {
        const int i = e >> 6, j = e & 63;
        wl0[e] = m0w[e] * sc0[i] * d0[j] * modv[i];
    }
    for (int e = t; e < 4096; e += 1024) {
        const int i = e >> 6, j = e & 63;
        wl1[e] = m1w[e] * sc1[i] * d1[j];
    }
    {
        const int i = t >> 4, j = t & 15;
        wl2[t] = (j < 3) ? m2w[i * 3 + j] * sc2[i] * d2[j] : 0.0f;
    }
    __syncthreads();

    // ---- Pack Wᵀ A-fragments (R12/R13-verified layout, byte-identical)
    ushort_t* outb = wsf + b * BSTRIDE;
    if (t < 896) {
        const int f = t >> 6, lane = t & 63;
        const int gg = lane >> 4, cc = lane & 15;   // cc = A row, k = 8*gg+e
        bf16x8 hv, lv;
#pragma unroll
        for (int e = 0; e < 8; ++e) {
            float wv;
            if (f < 4) {
                const int m = f;
                const int ch = 8 * (cc >> 2) + (cc & 3) + 4 * (m & 1) + 32 * (m >> 1);
                wv = wl0[(8 * gg + e) * 64 + ch];
            } else if (f < 12) {
                const int m = (f - 4) >> 1, kf = (f - 4) & 1;
                const int ch = 8 * (cc >> 2) + (cc & 3) + 4 * (m & 1) + 32 * (m >> 1);
                wv = wl1[(32 * kf + 8 * gg + e) * 64 + ch];
            } else {
                const int kf = f - 12;
                wv = wl2[(32 * kf + 8 * gg + e) * 16 + cc];
            }
            const ushort_t hh = f2bf(wv);
            hv[e] = (short)hh;
            lv[e] = (short)f2bf(wv - bf2f(hh));
        }
        *(bf16x8*)(outb + f * 1024 + lane * 8) = hv;
        *(bf16x8*)(outb + f * 1024 + 512 + lane * 8) = lv;
    }
}

// Swapped-operand MFMA chain (R17: best passing configuration, byte-identical).
__global__ __launch_bounds__(256) void k_main(
    const float* __restrict__ base_tables,
    const ushort_t* __restrict__ wsf,
    const float* __restrict__ m0b,
    const float* __restrict__ m1b,
    const float* __restrict__ m2b,
    float* __restrict__ out,
    ResPack rp)
{
    const int t = threadIdx.x;
    const int w = t >> 6;
    const int l = t & 63;
    const int g = l >> 4;
    const int c = l & 15;
    const int tile_base = blockIdx.x * 64 + w * 16;

    const int apx = tile_base + c;
    const float cx = ((float)(apx & 255) + 0.5f) * (1.0f / 256.0f);
    const float cy = ((float)(apx >> 8) + 0.5f) * (1.0f / 256.0f);
    bf16x8 rf_hi;
#pragma unroll
    for (int d = 0; d < 4; ++d) {
        float r1 = rp.rm1[d];
        r1 = (g == 1) ? rp.rm1[4 + d] : r1;
        r1 = (g == 2) ? rp.rm1[8 + d] : r1;
        r1 = (g == 3) ? rp.rm1[12 + d] : r1;
        const float sx = cx * r1, sy = cy * r1;
        const float pxf = floorf(sx), pyf = floorf(sy);
        const float fx = sx - pxf, fy = sy - pyf;
        const unsigned x0 = (unsigned)pxf, y0 = (unsigned)pyf;
        const unsigned x1 = x0 + 1u, y1 = y0 + 1u;
        const unsigned hy0 = y0 * P2H, hy1 = y1 * P2H;
        const float2* tab = reinterpret_cast<const float2*>(base_tables) + ((4 * g + d) << 14);
        const float2 f00 = tab[(x0 ^ hy0) & (TSZ - 1)];
        const float2 f01 = tab[(x0 ^ hy1) & (TSZ - 1)];
        const float2 f10 = tab[(x1 ^ hy0) & (TSZ - 1)];
        const float2 f11 = tab[(x1 ^ hy1) & (TSZ - 1)];
        const float w00 = (1.0f - fx) * (1.0f - fy);
        const float w01 = (1.0f - fx) * fy;
        const float w10 = fx * (1.0f - fy);
        const float w11 = fx * fy;
        const float v0 = w00 * f00.x + w01 * f01.x + w10 * f10.x + w11 * f11.x;
        const float v1 = w00 * f00.y + w01 * f01.y + w10 * f10.y + w11 * f11.y;
        rf_hi[2 * d]     = (short)f2bf(v0);
        rf_hi[2 * d + 1] = (short)f2bf(v1);
    }

    float b0v[4][4], b1v[4][4];
#pragma unroll
    for (int m = 0; m < 4; ++m)
#pragma unroll
        for (int q = 0; q < 4; ++q) {
            const int ch = 8 * g + q + 4 * (m & 1) + 32 * (m >> 1);
            b0v[m][q] = m0b[ch];
            b1v[m][q] = m1b[ch];
        }
    const floatx4 acc2init = (g == 0)
        ? (floatx4){ m2b[0], m2b[1], m2b[2], 0.0f }
        : (floatx4){ 0.0f, 0.0f, 0.0f, 0.0f };

#pragma unroll 2
    for (int b = 0; b < BATCH; ++b) {
        const ushort_t* F = wsf + b * BSTRIDE + l * 8;
#define LDF(fi, which) (*(const bf16x8*)(F + (fi) * 1024 + (which) * 512))

        // ---- layer 0: W hi only
        floatx4 acc0[4];
#pragma unroll
        for (int m = 0; m < 4; ++m) {
            acc0[m] = (floatx4){ b0v[m][0], b0v[m][1], b0v[m][2], b0v[m][3] };
            acc0[m] = __builtin_amdgcn_mfma_f32_16x16x32_bf16(LDF(m, 0), rf_hi, acc0[m], 0, 0, 0);
        }
        uintx4 u0, u1;
#pragma unroll
        for (int j = 0; j < 4; ++j) {
            u0[j] = cvt_pk_bf16(lrelu(acc0[j >> 1][(j & 1) * 2 + 0]),
                                lrelu(acc0[j >> 1][(j & 1) * 2 + 1]));
            u1[j] = cvt_pk_bf16(lrelu(acc0[2 + (j >> 1)][(j & 1) * 2 + 0]),
                                lrelu(acc0[2 + (j >> 1)][(j & 1) * 2 + 1]));
        }
        const bf16x8 h1f0 = __builtin_bit_cast(bf16x8, u0);
        const bf16x8 h1f1 = __builtin_bit_cast(bf16x8, u1);

        // ---- layer 1: W hi only
        floatx4 acc1[4];
#pragma unroll
        for (int m = 0; m < 4; ++m) {
            acc1[m] = (floatx4){ b1v[m][0], b1v[m][1], b1v[m][2], b1v[m][3] };
            acc1[m] = __builtin_amdgcn_mfma_f32_16x16x32_bf16(LDF(4 + 2 * m, 0), h1f0, acc1[m], 0, 0, 0);
            acc1[m] = __builtin_amdgcn_mfma_f32_16x16x32_bf16(LDF(5 + 2 * m, 0), h1f1, acc1[m], 0, 0, 0);
        }
        uintx4 v0, v1;
#pragma unroll
        for (int j = 0; j < 4; ++j) {
            v0[j] = cvt_pk_bf16(lrelu(acc1[j >> 1][(j & 1) * 2 + 0]),
                                lrelu(acc1[j >> 1][(j & 1) * 2 + 1]));
            v1[j] = cvt_pk_bf16(lrelu(acc1[2 + (j >> 1)][(j & 1) * 2 + 0]),
                                lrelu(acc1[2 + (j >> 1)][(j & 1) * 2 + 1]));
        }
        const bf16x8 h2f0 = __builtin_bit_cast(bf16x8, v0);
        const bf16x8 h2f1 = __builtin_bit_cast(bf16x8, v1);

        // ---- layer 2: W hi only
        floatx4 acc2 = acc2init;
        acc2 = __builtin_amdgcn_mfma_f32_16x16x32_bf16(LDF(12, 0), h2f0, acc2, 0, 0, 0);
        acc2 = __builtin_amdgcn_mfma_f32_16x16x32_bf16(LDF(13, 0), h2f1, acc2, 0, 0, 0);

        if (g == 0) {
            out[(b * 3 + 0) * NPIX + tile_base + c] = acc2[0];
            out[(b * 3 + 1) * NPIX + tile_base + c] = acc2[1];
            out[(b * 3 + 2) * NPIX + tile_base + c] = acc2[2];
        }
#undef LDF
    }
}

extern "C" void kernel_launch(void* const* d_in, const int* in_sizes, int n_in,
                              void* d_out, int out_size, void* d_ws, size_t ws_size,
                              hipStream_t stream) {
    const float* z    = (const float*)d_in[0];
    const float* w1   = (const float*)d_in[1];
    const float* b1   = (const float*)d_in[2];
    const float* w2   = (const float*)d_in[3];
    const float* b2   = (const float*)d_in[4];
    const float* w3   = (const float*)d_in[5];
    const float* b3   = (const float*)d_in[6];
    const float* bt   = (const float*)d_in[7];
    const float* genw = (const float*)d_in[8];
    const float* a0w  = (const float*)d_in[9];
    const float* a0b  = (const float*)d_in[10];
    const float* m0w  = (const float*)d_in[11];
    const float* m0b  = (const float*)d_in[12];
    const float* a1w  = (const float*)d_in[13];
    const float* a1b  = (const float*)d_in[14];
    const float* m1w  = (const float*)d_in[15];
    const float* m1b  = (const float*)d_in[16];
    const float* a2w  = (const float*)d_in[17];
    const float* a2b  = (const float*)d_in[18];
    const float* m2w  = (const float*)d_in[19];
    const float* m2b  = (const float*)d_in[20];
    ushort_t* wsf = (ushort_t*)d_ws;
    float* out = (float*)d_out;

    ResPack rp;
    const double bfac = exp((log(256.0) - log(16.0)) / 15.0);
    for (int lv = 0; lv < LVL; ++lv) {
        const double v = floor(16.0 * pow(bfac, (double)lv));
        rp.rm1[lv] = (float)v - 1.0f;
    }

    hipLaunchKernelGGL(k_setup, dim3(BATCH), dim3(1024), 0, stream,
                       z, w1, b1, w2, b2, w3, b3, genw,
                       a0w, a0b, m0w, a1w, a1b, m1w, a2w, a2b, m2w, wsf);

    hipLaunchKernelGGL(k_main, dim3(NPIX / 64), dim3(256), 0, stream,
                       bt, wsf, m0b, m1b, m2b, out, rp);
}